// Round 9
// baseline (215.119 us; speedup 1.0000x reference)
//
#include <hip/hip_runtime.h>
#include <math.h>

#define TH 65536
#define SD 128
#define AD 8
#define HD 256

constexpr float GAMMA  = 0.99f;
constexpr float LMBDA  = 0.95f;
constexpr float EPSC   = 0.2f;
constexpr float VFC    = 0.5f;
constexpr float ENTC   = 0.01f;
constexpr float LOG2PI = 1.8378770664093453f;

typedef _Float16 half8 __attribute__((ext_vector_type(8)));
typedef __fp16 fp16x2 __attribute__((ext_vector_type(2)));
typedef __attribute__((ext_vector_type(4))) float f32x4;

// workspace layout (float offsets)
constexpr size_t WS_VALUES = 0;        // TH+1 (reserve 65540)
constexpr size_t WS_RATIO  = 131080;   // TH
constexpr size_t WS_CHP    = 196616;   // 64
constexpr size_t WS_CHB    = 196680;   // 64
constexpr size_t WS_SCAL   = 196744;   // 8: [4] = arrival ticket
constexpr size_t WS_BF     = 196752;   // f16 weights (196608 ushorts = 98304 floats)
constexpr size_t SW_PIW1 = 0;          // 32768
constexpr size_t SW_PIW2 = 32768;      // 65536
constexpr size_t SW_VW1  = 98304;      // 32768
constexpr size_t SW_VW2  = 131072;     // 65536 -> total 196608 ushorts
constexpr size_t WS_S1P  = 295056;     // 64 per-block sum partials
constexpr size_t WS_S2P  = 295120;     // 64 sumsq partials
constexpr size_t WS_VFP  = 295184;     // 64 huber partials
constexpr size_t WS_PGP  = 295248;     // 64 pg partials -> end 295312

__device__ __forceinline__ unsigned pk2h(float a, float b) {
    fp16x2 h = __builtin_amdgcn_cvt_pkrtz(a, b);
    return __builtin_bit_cast(unsigned, h);
}

// fast tanh, clamp-free: 1 - 2/(e^{2x}+1).
__device__ __forceinline__ float ftanh(float x) {
    float e = __expf(x + x);
    return fmaf(-2.f, __builtin_amdgcn_rcpf(e + 1.f), 1.f);
}

// relaxed agent-scope load (cross-block visibility within one kernel)
__device__ __forceinline__ float atomLoad(const float* p) {
    return __hip_atomic_load(p, __ATOMIC_RELAXED, __HIP_MEMORY_SCOPE_AGENT);
}

// async-stage one 16 KB weight chunk (16 fragments of 1 KB) into LDS.
// Wave w issues fragments w*4 .. w*4+3. Source is per-lane (base + lane*16);
// LDS dest is wave-uniform; HW scatters lane i at dest + i*16 (linear layout
// matches the fragment layout exactly).
__device__ __forceinline__ void stage_chunk(
    const unsigned short* __restrict__ W, int ks,
    unsigned short* lbuf, int wave, int lane)
{
    const char* src = (const char*)W + (size_t)ks * 16384
                    + (size_t)wave * 4096 + (size_t)lane * 16;
    char* dst = (char*)lbuf + wave * 4096;
#pragma unroll
    for (int f = 0; f < 4; ++f) {
        __builtin_amdgcn_global_load_lds(
            (const __attribute__((address_space(1))) void*)(src + f * 1024),
            (__attribute__((address_space(3))) void*)(dst + f * 1024),
            16, 0, 0);
    }
}

// ------------- weight swizzle: coalesced f32 reads, scattered 2B f16 stores
__global__ __launch_bounds__(256) void swizzle_kernel(
    const float* __restrict__ piW1, const float* __restrict__ vW1,
    const float* __restrict__ piW2, const float* __restrict__ vW2,
    unsigned short* __restrict__ dPiW1, unsigned short* __restrict__ dVW1,
    unsigned short* __restrict__ dPiW2, unsigned short* __restrict__ dVW2,
    float* __restrict__ scal)
{
    if (blockIdx.x == 0 && threadIdx.x < 8) scal[threadIdx.x] = 0.f;
    int g = blockIdx.x * 256 + threadIdx.x;   // float4 id, 49152 total
    const float* S; unsigned short* D; int lo;
    if      (g <  8192) { S = piW1; D = dPiW1; lo = 0;     }
    else if (g < 24576) { S = piW2; D = dPiW2; lo = 8192;  }
    else if (g < 32768) { S = vW1;  D = dVW1;  lo = 24576; }
    else                { S = vW2;  D = dVW2;  lo = 32768; }
    int q = g - lo;
    int k = q >> 6, n4 = (q & 63) * 4;        // 4 consecutive n, same nt
    float4 v = *(const float4*)(S + (size_t)k * HD + n4);
    int ks = k >> 5, kq = (k >> 3) & 3, j = k & 7;
    int nt = n4 >> 4, nr = n4 & 15;
    unsigned short* base = D + ((size_t)(ks * 16 + nt) * 64 + kq * 16 + nr) * 8 + j;
    unsigned p01 = pk2h(v.x, v.y);
    unsigned p23 = pk2h(v.z, v.w);
    base[0]  = (unsigned short)(p01 & 0xffff);
    base[8]  = (unsigned short)(p01 >> 16);
    base[16] = (unsigned short)(p23 & 0xffff);
    base[24] = (unsigned short)(p23 >> 16);
}

// store 4 row-consecutive tanh outputs into LDS f16 (pk convert)
__device__ __forceinline__ void store4(unsigned short* dst, int stride,
                                       float t0, float t1, float t2, float t3)
{
    unsigned p01 = pk2h(t0, t1), p23 = pk2h(t2, t3);
    dst[0]          = (unsigned short)(p01 & 0xffff);
    dst[stride]     = (unsigned short)(p01 >> 16);
    dst[2 * stride] = (unsigned short)(p23 & 0xffff);
    dst[3 * stride] = (unsigned short)(p23 >> 16);
}

// ------------- fused pi+v MLP on 32-row tiles, LDS-staged weights
// 256 threads = 4 waves = 2 rowgroups x 2 colhalves.
// B fragments are async-staged (global_load_lds) into a 2 x 16 KB LDS
// double buffer, one 16 KB chunk per ks step, chained continuously across
// layers and nets: piW1(4) -> piW2(8) -> vW1(4) -> vW2(8).
// Each fragment crosses L2 ONCE per block (was twice), and the load queue
// stays deep (drain only at the per-step barrier).
__global__ __launch_bounds__(256, 3) void mlp_fused_kernel(
    const float* __restrict__ X, const float* __restrict__ Xlast,
    const unsigned short* __restrict__ piW1s, const float* __restrict__ pib1,
    const unsigned short* __restrict__ piW2s, const float* __restrict__ pib2,
    const float* __restrict__ muW, const float* __restrict__ mub,
    const float* __restrict__ logstd,
    const float* __restrict__ act, const float* __restrict__ lpold,
    const unsigned short* __restrict__ vW1s, const float* __restrict__ vb1,
    const unsigned short* __restrict__ vW2s, const float* __restrict__ vb2,
    const float* __restrict__ vhW, const float* __restrict__ vhb,
    float* __restrict__ values, float* __restrict__ ratio)
{
    __shared__ __align__(16) unsigned short wbuf[2][8192];  // 2 x 16 KB stage
    __shared__ __align__(16) unsigned short h1[32 * 264];   // 16896 B
    __shared__ float cmb[32 * 8];                           // 1024 B
    __shared__ float val[32];                               // 128 B
    const int tid = threadIdx.x;
    const int lane = tid & 63, wave = tid >> 6;
    const int l15 = lane & 15, quad = lane >> 4;
    const int rowgrp = wave >> 1, colhalf = wave & 1;   // 2 x 2 over 32 rows
    const bool vonly = (blockIdx.x == gridDim.x - 1);
    const float* Xp = vonly ? Xlast : X + (size_t)blockIdx.x * 32 * SD;
    const int nrows = vonly ? 1 : 32;
    const int vout0 = vonly ? TH : blockIdx.x * 32;

    if (tid < 32) val[tid] = 0.f;
    cmb[tid] = 0.f;

    // issue first chunk stage (piW1 ks0; vW1 ks0 for the tail block)
    stage_chunk(vonly ? vW1s : piW1s, 0, wbuf[0], wave, lane);

    // layer-1 A fragments: row rowgrp*16+l15, cols ks*32+quad*8 .. +7
    const int rr = rowgrp * 16 + l15;
    const float* xrow = Xp + (size_t)(rr < nrows ? rr : 0) * SD;
    half8 afr[4];
#pragma unroll
    for (int ks = 0; ks < 4; ++ks) {
        float4 v0 = *(const float4*)(xrow + ks * 32 + quad * 8);
        float4 v1 = *(const float4*)(xrow + ks * 32 + quad * 8 + 4);
        if (rr >= nrows) { v0 = make_float4(0.f, 0.f, 0.f, 0.f); v1 = v0; }
        uint4 u = make_uint4(pk2h(v0.x, v0.y), pk2h(v0.z, v0.w),
                             pk2h(v1.x, v1.y), pk2h(v1.z, v1.w));
        afr[ks] = __builtin_bit_cast(half8, u);
    }

    f32x4 acc[8];
    __syncthreads();   // drain: wbuf[0] chunk landed

    if (!vonly) {
        // ---- pi layer 1: 4 ks chunks
#pragma unroll
        for (int nt = 0; nt < 8; ++nt) acc[nt] = (f32x4){0.f, 0.f, 0.f, 0.f};
#pragma unroll
        for (int ks = 0; ks < 4; ++ks) {
            if (ks < 3) stage_chunk(piW1s, ks + 1, wbuf[(ks + 1) & 1], wave, lane);
            else        stage_chunk(piW2s, 0, wbuf[0], wave, lane);
            const half8* bb = (const half8*)wbuf[ks & 1];
#pragma unroll
            for (int ntl = 0; ntl < 8; ++ntl)
                acc[ntl] = __builtin_amdgcn_mfma_f32_16x16x32_f16(
                    afr[ks], bb[(colhalf * 8 + ntl) * 64 + lane], acc[ntl], 0, 0, 0);
            __syncthreads();
        }
#pragma unroll
        for (int ntl = 0; ntl < 8; ++ntl) {
            int col = (colhalf * 8 + ntl) * 16 + l15;
            float bb = pib1[col];
            store4(&h1[(rowgrp * 16 + quad * 4) * 264 + col], 264,
                   ftanh(acc[ntl][0] + bb), ftanh(acc[ntl][1] + bb),
                   ftanh(acc[ntl][2] + bb), ftanh(acc[ntl][3] + bb));
        }
        __syncthreads();
        // ---- pi layer 2: 8 ks chunks (A from h1)
#pragma unroll
        for (int nt = 0; nt < 8; ++nt) acc[nt] = (f32x4){0.f, 0.f, 0.f, 0.f};
        {
            const unsigned short* Ap = h1 + (rowgrp * 16 + l15) * 264 + quad * 8;
#pragma unroll
            for (int ks = 0; ks < 8; ++ks) {
                if (ks < 7) stage_chunk(piW2s, ks + 1, wbuf[(ks + 1) & 1], wave, lane);
                else        stage_chunk(vW1s, 0, wbuf[0], wave, lane);
                half8 af = *(const half8*)(Ap + ks * 32);
                const half8* bb = (const half8*)wbuf[ks & 1];
#pragma unroll
                for (int ntl = 0; ntl < 8; ++ntl)
                    acc[ntl] = __builtin_amdgcn_mfma_f32_16x16x32_f16(
                        af, bb[(colhalf * 8 + ntl) * 64 + lane], acc[ntl], 0, 0, 0);
                __syncthreads();
            }
        }
        // ---- mu head partials (fp32 VALU dot over this wave's 128 cols)
        float pm[4][8];
#pragma unroll
        for (int rg = 0; rg < 4; ++rg)
#pragma unroll
            for (int aj = 0; aj < 8; ++aj) pm[rg][aj] = 0.f;
#pragma unroll
        for (int ntl = 0; ntl < 8; ++ntl) {
            int col = (colhalf * 8 + ntl) * 16 + l15;
            float bb = pib2[col];
            float4 w0 = *(const float4*)(muW + (size_t)col * AD);
            float4 w1 = *(const float4*)(muW + (size_t)col * AD + 4);
            float wv[8] = {w0.x, w0.y, w0.z, w0.w, w1.x, w1.y, w1.z, w1.w};
#pragma unroll
            for (int rg = 0; rg < 4; ++rg) {
                float hv = ftanh(acc[ntl][rg] + bb);
#pragma unroll
                for (int aj = 0; aj < 8; ++aj) pm[rg][aj] = fmaf(hv, wv[aj], pm[rg][aj]);
            }
        }
#pragma unroll
        for (int off = 8; off >= 1; off >>= 1)
#pragma unroll
            for (int rg = 0; rg < 4; ++rg)
#pragma unroll
                for (int aj = 0; aj < 8; ++aj)
                    pm[rg][aj] += __shfl_xor(pm[rg][aj], off, 16);
        if (l15 == 0) {
#pragma unroll
            for (int rg = 0; rg < 4; ++rg) {
                int rowi = rowgrp * 16 + quad * 4 + rg;
#pragma unroll
                for (int aj = 0; aj < 8; ++aj)
                    atomicAdd(&cmb[rowi * 8 + aj], pm[rg][aj]);
            }
        }
        __syncthreads();
        // ---- per-row log-prob ratio (reads cmb only)
        if (tid < 32) {
            int row = blockIdx.x * 32 + tid;
            const float* ar = act + (size_t)row * AD;
            float lp = 0.f;
#pragma unroll
            for (int aj = 0; aj < 8; ++aj) {
                float ls = logstd[aj];
                float mu = cmb[tid * 8 + aj] + mub[aj];
                float z = (ar[aj] - mu) * __expf(-ls);
                lp += -0.5f * z * z - ls;
            }
            lp -= 4.f * LOG2PI;
            ratio[row] = __expf(lp - lpold[row]);
        }
        __syncthreads();    // h1 reads done before v layer 1 overwrites
    }

    // ---- v layer 1: 4 ks chunks (vW1 ks0 already staged in wbuf[0])
#pragma unroll
    for (int nt = 0; nt < 8; ++nt) acc[nt] = (f32x4){0.f, 0.f, 0.f, 0.f};
#pragma unroll
    for (int ks = 0; ks < 4; ++ks) {
        if (ks < 3) stage_chunk(vW1s, ks + 1, wbuf[(ks + 1) & 1], wave, lane);
        else        stage_chunk(vW2s, 0, wbuf[0], wave, lane);
        const half8* bb = (const half8*)wbuf[ks & 1];
#pragma unroll
        for (int ntl = 0; ntl < 8; ++ntl)
            acc[ntl] = __builtin_amdgcn_mfma_f32_16x16x32_f16(
                afr[ks], bb[(colhalf * 8 + ntl) * 64 + lane], acc[ntl], 0, 0, 0);
        __syncthreads();
    }
#pragma unroll
    for (int ntl = 0; ntl < 8; ++ntl) {
        int col = (colhalf * 8 + ntl) * 16 + l15;
        float bb = vb1[col];
        store4(&h1[(rowgrp * 16 + quad * 4) * 264 + col], 264,
               ftanh(acc[ntl][0] + bb), ftanh(acc[ntl][1] + bb),
               ftanh(acc[ntl][2] + bb), ftanh(acc[ntl][3] + bb));
    }
    __syncthreads();
    // ---- v layer 2: 8 ks chunks + value head
#pragma unroll
    for (int nt = 0; nt < 8; ++nt) acc[nt] = (f32x4){0.f, 0.f, 0.f, 0.f};
    {
        const unsigned short* Ap = h1 + (rowgrp * 16 + l15) * 264 + quad * 8;
#pragma unroll
        for (int ks = 0; ks < 8; ++ks) {
            if (ks < 7) stage_chunk(vW2s, ks + 1, wbuf[(ks + 1) & 1], wave, lane);
            half8 af = *(const half8*)(Ap + ks * 32);
            const half8* bb = (const half8*)wbuf[ks & 1];
#pragma unroll
            for (int ntl = 0; ntl < 8; ++ntl)
                acc[ntl] = __builtin_amdgcn_mfma_f32_16x16x32_f16(
                    af, bb[(colhalf * 8 + ntl) * 64 + lane], acc[ntl], 0, 0, 0);
            __syncthreads();
        }
    }
    float vp[4] = {0.f, 0.f, 0.f, 0.f};
#pragma unroll
    for (int ntl = 0; ntl < 8; ++ntl) {
        int col = (colhalf * 8 + ntl) * 16 + l15;
        float bb = vb2[col], w = vhW[col];
#pragma unroll
        for (int rg = 0; rg < 4; ++rg) vp[rg] += ftanh(acc[ntl][rg] + bb) * w;
    }
#pragma unroll
    for (int off = 8; off >= 1; off >>= 1)
#pragma unroll
        for (int rg = 0; rg < 4; ++rg) vp[rg] += __shfl_xor(vp[rg], off, 16);
    if (l15 == 0) {
#pragma unroll
        for (int rg = 0; rg < 4; ++rg)
            atomicAdd(&val[rowgrp * 16 + quad * 4 + rg], vp[rg]);
    }
    __syncthreads();
    if (tid < nrows)
        values[vout0 + tid] = val[tid] + vhb[0];
}

// ------------- GAE helpers (unchanged from R7)
__device__ __forceinline__ void gae_block_scan(
    const float* __restrict__ rw, const float* __restrict__ m,
    const float* __restrict__ values, int t0, int j,
    float* sp_, float* sb_, float* ds, float* ms)
{
    float4 vv = *(const float4*)(values + t0);
    float v4 = values[t0 + 4];
    float4 rr = *(const float4*)(rw + t0);
    float4 mm = *(const float4*)(m + t0);
    float vs[5] = {vv.x, vv.y, vv.z, vv.w, v4};
    float rs[4] = {rr.x, rr.y, rr.z, rr.w};
    ms[0] = mm.x; ms[1] = mm.y; ms[2] = mm.z; ms[3] = mm.w;
    const float g = GAMMA * LMBDA;
#pragma unroll
    for (int i = 0; i < 4; ++i)
        ds[i] = rs[i] + GAMMA * vs[i + 1] * ms[i] - vs[i];

    float P = 1.f, B = 0.f;
#pragma unroll
    for (int i = 3; i >= 0; --i) {
        float p = g * ms[i];
        B = ds[i] + p * B;
        P = p * P;
    }
    sp_[j] = P; sb_[j] = B;
    __syncthreads();
    for (int dstep = 1; dstep < 256; dstep <<= 1) {
        float pj = sp_[j], bj = sb_[j], pk = 1.f, bk = 0.f;
        if (j + dstep < 256) { pk = sp_[j + dstep]; bk = sb_[j + dstep]; }
        __syncthreads();
        sp_[j] = pj * pk;
        sb_[j] = bj + pj * bk;
        __syncthreads();
    }
}

__device__ __forceinline__ float gae_carry(
    const float* __restrict__ chunkP, const float* __restrict__ chunkB,
    int j, int bid, float* cp, float* cb, float* bcast)
{
    if (j < 64) { cp[j] = chunkP[j]; cb[j] = chunkB[j]; }
    __syncthreads();
    if (j == 0) {
        float A = 0.f;
        for (int c = 63; c > bid; --c) A = cb[c] + cp[c] * A;
        bcast[0] = A;
    }
    __syncthreads();
    return bcast[0];
}

// ------------- K1: per-chunk scan totals
__global__ __launch_bounds__(256) void gae_scan_kernel(
    const float* __restrict__ rw, const float* __restrict__ m,
    const float* __restrict__ values,
    float* __restrict__ chunkP, float* __restrict__ chunkB)
{
    __shared__ float sp_[256], sb_[256];
    const int j = threadIdx.x;
    float ds[4], ms[4];
    gae_block_scan(rw, m, values, blockIdx.x * 1024 + j * 4, j, sp_, sb_, ds, ms);
    if (j == 0) { chunkP[blockIdx.x] = sp_[0]; chunkB[blockIdx.x] = sb_[0]; }
}

// ------------- K2: carry + advantages + per-block sum/sumsq/huber partials
__global__ __launch_bounds__(256) void gae_mid_kernel(
    const float* __restrict__ rw, const float* __restrict__ m,
    const float* __restrict__ values,
    const float* __restrict__ chunkP, const float* __restrict__ chunkB,
    float* __restrict__ s1p, float* __restrict__ s2p, float* __restrict__ vfp)
{
    __shared__ float sp_[256], sb_[256];
    __shared__ float cp[64], cb[64];
    __shared__ float red[12];
    __shared__ float bcast[1];
    const int j = threadIdx.x;
    const float g = GAMMA * LMBDA;
    float ds[4], ms[4];
    gae_block_scan(rw, m, values, blockIdx.x * 1024 + j * 4, j, sp_, sb_, ds, ms);
    const float carry = gae_carry(chunkP, chunkB, j, blockIdx.x, cp, cb, bcast);

    float Pe = 1.f, Be = 0.f;
    if (j < 255) { Pe = sp_[j + 1]; Be = sb_[j + 1]; }
    float A = Be + Pe * carry;
    float s1 = 0.f, s2 = 0.f, vf = 0.f;
#pragma unroll
    for (int i = 3; i >= 0; --i) {
        A = ds[i] + g * ms[i] * A;
        float ab = fabsf(A);
        vf += (ab < 1.f) ? 0.5f * A * A : ab - 0.5f;
        s1 += A;
        s2 += A * A;
    }
#pragma unroll
    for (int off = 32; off >= 1; off >>= 1) {
        s1 += __shfl_down(s1, off, 64);
        s2 += __shfl_down(s2, off, 64);
        vf += __shfl_down(vf, off, 64);
    }
    if ((j & 63) == 0) {
        int w = j >> 6;
        red[w] = s1; red[4 + w] = s2; red[8 + w] = vf;
    }
    __syncthreads();
    if (j == 0) {
        s1p[blockIdx.x] = red[0] + red[1] + red[2] + red[3];
        s2p[blockIdx.x] = red[4] + red[5] + red[6] + red[7];
        vfp[blockIdx.x] = red[8] + red[9] + red[10] + red[11];
    }
}

// ------------- K3: normalize + clipped PG; last-arrival block writes the loss
__global__ __launch_bounds__(256) void gae_fin_kernel(
    const float* __restrict__ rw, const float* __restrict__ m,
    const float* __restrict__ values, const float* __restrict__ ratio,
    const float* __restrict__ logstd,
    const float* __restrict__ chunkP, const float* __restrict__ chunkB,
    const float* __restrict__ s1p, const float* __restrict__ s2p,
    const float* __restrict__ vfp,
    float* __restrict__ pgp, float* __restrict__ scal, float* __restrict__ out)
{
    __shared__ float sp_[256], sb_[256];
    __shared__ float cp[64], cb[64];
    __shared__ float red[4];
    __shared__ float bcast[4];
    const int j = threadIdx.x;
    const int t0 = blockIdx.x * 1024 + j * 4;
    const float g = GAMMA * LMBDA;
    float ds[4], ms[4];
    gae_block_scan(rw, m, values, t0, j, sp_, sb_, ds, ms);
    const float carry = gae_carry(chunkP, chunkB, j, blockIdx.x, cp, cb, bcast);

    if (j < 64) {
        float a = s1p[j], b = s2p[j], c = vfp[j];
#pragma unroll
        for (int off = 32; off >= 1; off >>= 1) {
            a += __shfl_down(a, off, 64);
            b += __shfl_down(b, off, 64);
            c += __shfl_down(c, off, 64);
        }
        if (j == 0) { bcast[1] = a; bcast[2] = b; bcast[3] = c; }
    }
    __syncthreads();
    const float ssum = bcast[1], ssq = bcast[2], vfs = bcast[3];
    const float meanA = ssum / (float)TH;
    const float varA = fmaxf((ssq - ssum * ssum / (float)TH) / (float)(TH - 1), 0.f);
    const float inv = 1.f / (sqrtf(varA) + 1e-8f);

    float Pe = 1.f, Be = 0.f;
    if (j < 255) { Pe = sp_[j + 1]; Be = sb_[j + 1]; }
    float A = Be + Pe * carry;
    float a4[4];
#pragma unroll
    for (int i = 3; i >= 0; --i) {
        A = ds[i] + g * ms[i] * A;
        a4[i] = A;
    }

    float4 r4 = *(const float4*)(ratio + t0);
    float rt[4] = {r4.x, r4.y, r4.z, r4.w};
    float pg = 0.f;
#pragma unroll
    for (int i = 0; i < 4; ++i) {
        float aN = (a4[i] - meanA) * inv;
        float rc = fminf(fmaxf(rt[i], 1.f - EPSC), 1.f + EPSC);
        pg -= fminf(rt[i] * aN, rc * aN);
    }
#pragma unroll
    for (int off = 32; off >= 1; off >>= 1) pg += __shfl_down(pg, off, 64);
    if ((j & 63) == 0) red[j >> 6] = pg;
    __syncthreads();
    if (j == 0) {
        pgp[blockIdx.x] = red[0] + red[1] + red[2] + red[3];
        __threadfence();
        float old = atomicAdd(&scal[4], 1.f);
        if (old == 63.f) {   // last arrival: all pgp stores visible
            float pgs = 0.f;
            for (int c = 0; c < 64; ++c) pgs += atomLoad(&pgp[c]);
            float ls = 0.f;
#pragma unroll
            for (int jj = 0; jj < AD; ++jj) ls += logstd[jj];
            float entropy = 0.5f + 0.5f * LOG2PI + ls / (float)AD;
            out[0] = pgs / (float)TH + VFC * (vfs / (float)TH) - ENTC * entropy;
        }
    }
}

extern "C" void kernel_launch(void* const* d_in, const int* in_sizes, int n_in,
                              void* d_out, int out_size, void* d_ws, size_t ws_size,
                              hipStream_t stream) {
    const float* s      = (const float*)d_in[0];
    const float* a      = (const float*)d_in[1];
    const float* r      = (const float*)d_in[2];
    const float* sp     = (const float*)d_in[3];
    const float* lpold  = (const float*)d_in[4];
    const float* dmask  = (const float*)d_in[5];
    const float* piW1   = (const float*)d_in[6];
    const float* pib1   = (const float*)d_in[7];
    const float* piW2   = (const float*)d_in[8];
    const float* pib2   = (const float*)d_in[9];
    const float* muW    = (const float*)d_in[10];
    const float* mub    = (const float*)d_in[11];
    const float* logstd = (const float*)d_in[12];
    const float* vW1    = (const float*)d_in[13];
    const float* vb1    = (const float*)d_in[14];
    const float* vW2    = (const float*)d_in[15];
    const float* vb2    = (const float*)d_in[16];
    const float* vhW    = (const float*)d_in[17];
    const float* vhb    = (const float*)d_in[18];

    float* ws      = (float*)d_ws;
    float* values  = ws + WS_VALUES;
    float* ratio   = ws + WS_RATIO;
    float* chunkP  = ws + WS_CHP;
    float* chunkB  = ws + WS_CHB;
    float* scal    = ws + WS_SCAL;
    float* s1p     = ws + WS_S1P;
    float* s2p     = ws + WS_S2P;
    float* vfp     = ws + WS_VFP;
    float* pgp     = ws + WS_PGP;
    unsigned short* bfbase = (unsigned short*)(ws + WS_BF);
    unsigned short* dPiW1 = bfbase + SW_PIW1;
    unsigned short* dPiW2 = bfbase + SW_PIW2;
    unsigned short* dVW1  = bfbase + SW_VW1;
    unsigned short* dVW2  = bfbase + SW_VW2;

    swizzle_kernel<<<192, 256, 0, stream>>>(piW1, vW1, piW2, vW2,
                                            dPiW1, dVW1, dPiW2, dVW2, scal);

    mlp_fused_kernel<<<TH / 32 + 1, 256, 0, stream>>>(
        s, sp + (size_t)(TH - 1) * SD,
        dPiW1, pib1, dPiW2, pib2, muW, mub, logstd, a, lpold,
        dVW1, vb1, dVW2, vb2, vhW, vhb,
        values, ratio);

    gae_scan_kernel<<<64, 256, 0, stream>>>(r, dmask, values, chunkP, chunkB);
    gae_mid_kernel<<<64, 256, 0, stream>>>(r, dmask, values, chunkP, chunkB,
                                           s1p, s2p, vfp);
    gae_fin_kernel<<<64, 256, 0, stream>>>(r, dmask, values, ratio, logstd,
                                           chunkP, chunkB, s1p, s2p, vfp,
                                           pgp, scal, (float*)d_out);
}